// Round 2
// baseline (30.873 us; speedup 1.0000x reference)
//
#include <hip/hip_runtime.h>
#include <hip/hip_bf16.h>
#include <float.h>

typedef float f32x4 __attribute__((ext_vector_type(4)));

// Kernel 1: argmax over vocab for each (t, b) row, R rows per wave.
// x layout: (seq_len, batch, vocab) row-major. Output ml stored TRANSPOSED:
// ml[b * seq_len + t]. Also fills tokens[] with -1 (kernel 2 only scatters).
template <int R>
__global__ void ctc_argmax_kernel(const float* __restrict__ x,
                                  int* __restrict__ ml,
                                  int* __restrict__ tokens,
                                  int seq_len, int batch, int vocab) {
    const int lane = threadIdx.x & 63;
    const int wave = blockIdx.x * (blockDim.x >> 6) + (threadIdx.x >> 6);
    const int nrows = seq_len * batch;
    const int row0 = wave * R;

    // -1 fill of tokens (batch*seq_len ints) spread across the whole grid.
    const int gtid = blockIdx.x * blockDim.x + threadIdx.x;
    const int gstride = gridDim.x * blockDim.x;
    for (int i = gtid; i < nrows; i += gstride) tokens[i] = -1;

    if (row0 >= nrows) return;

    float best[R];
    int bidx[R];
#pragma unroll
    for (int r = 0; r < R; ++r) { best[r] = -FLT_MAX; bidx[r] = vocab; }

    const int vocab4 = vocab & ~3;
    // Main loop: R independent float4 loads per iteration (MLP), then compares.
    for (int base = lane * 4; base < vocab4; base += 256) {
        f32x4 v[R];
#pragma unroll
        for (int r = 0; r < R; ++r) {
            const int row = row0 + r;
            if (row < nrows) {
                v[r] = __builtin_nontemporal_load(
                    reinterpret_cast<const f32x4*>(x + (size_t)row * vocab + base));
            }
        }
#pragma unroll
        for (int r = 0; r < R; ++r) {
            if (row0 + r >= nrows) continue;
#pragma unroll
            for (int j = 0; j < 4; ++j) {
                if (v[r][j] > best[r]) { best[r] = v[r][j]; bidx[r] = base + j; }
            }
        }
    }
    // Scalar tail (vocab % 4 != 0). Tail indices exceed main-loop indices;
    // strict '>' keeps the earlier occurrence.
    for (int i = vocab4 + lane; i < vocab; i += 64) {
#pragma unroll
        for (int r = 0; r < R; ++r) {
            if (row0 + r >= nrows) continue;
            float v = x[(size_t)(row0 + r) * vocab + i];
            if (v > best[r]) { best[r] = v; bidx[r] = i; }
        }
    }

    // Wave butterfly reduce, R rows interleaved to hide shuffle latency.
    // Larger value wins; on tie, lower index wins (argmax first-occurrence).
#pragma unroll
    for (int off = 32; off >= 1; off >>= 1) {
#pragma unroll
        for (int r = 0; r < R; ++r) {
            float ov = __shfl_down(best[r], off, 64);
            int oi = __shfl_down(bidx[r], off, 64);
            if (ov > best[r] || (ov == best[r] && oi < bidx[r])) {
                best[r] = ov; bidx[r] = oi;
            }
        }
    }

    if (lane == 0) {
#pragma unroll
        for (int r = 0; r < R; ++r) {
            const int row = row0 + r;
            if (row < nrows) {
                const int t = row / batch;
                const int b = row - t * batch;
                ml[(size_t)b * seq_len + t] = bidx[r];
            }
        }
    }
}

// Kernel 2: per-batch removal of blanks and consecutive duplicates + left-pack.
// One block (256 threads) per batch element. tokens[] is pre-filled with -1.
__global__ void ctc_compact_kernel(const int* __restrict__ ml,
                                   const int* __restrict__ lengths,
                                   const int* __restrict__ blank_ptr,
                                   int* __restrict__ tokens,
                                   int* __restrict__ out_lengths,
                                   int seq_len, int batch) {
    constexpr int MAXPER = 16;
    const int b = blockIdx.x;
    if (b >= batch) return;
    const int blank = *blank_ptr;
    const int len = lengths[b];
    const int* row = ml + (size_t)b * seq_len;
    int* out = tokens + (size_t)b * seq_len;

    const int tid = threadIdx.x;
    const int nthr = blockDim.x;
    const int per = (seq_len + nthr - 1) / nthr;  // 8 for 2048/256

    // Each thread owns `per` consecutive timesteps [t0, t0+per).
    const int t0 = tid * per;
    int vals[MAXPER];
    unsigned keep_mask = 0;
    int cnt = 0;
    int prev = (t0 == 0) ? -1 : ((t0 - 1 < seq_len) ? row[t0 - 1] : -1);
    for (int j = 0; j < per; ++j) {
        const int t = t0 + j;
        if (t >= seq_len) break;
        const int v = row[t];
        const bool valid = t < len;
        const bool k = valid && (v != blank) && (prev == blank || v != prev);
        vals[j] = v;
        if (k) { keep_mask |= (1u << j); ++cnt; }
        prev = v;
    }

    // Block-wide exclusive prefix sum of cnt (in thread order).
    __shared__ int warp_sums[8];
    const int lane = tid & 63;
    const int wid = tid >> 6;
    int incl = cnt;
#pragma unroll
    for (int off = 1; off < 64; off <<= 1) {
        int n = __shfl_up(incl, off, 64);
        if (lane >= off) incl += n;
    }
    if (lane == 63) warp_sums[wid] = incl;
    __syncthreads();

    int wbase = 0;
    for (int w = 0; w < wid; ++w) wbase += warp_sums[w];
    int pos = wbase + incl - cnt;  // exclusive prefix for this thread

    for (int j = 0; j < per; ++j) {
        if (keep_mask & (1u << j)) out[pos++] = vals[j];
    }

    if (tid == 0) {
        int total = 0;
        const int nwaves = nthr >> 6;
        for (int w = 0; w < nwaves; ++w) total += warp_sums[w];
        out_lengths[b] = total;
    }
}

extern "C" void kernel_launch(void* const* d_in, const int* in_sizes, int n_in,
                              void* d_out, int out_size, void* d_ws, size_t ws_size,
                              hipStream_t stream) {
    const float* x = (const float*)d_in[0];
    const int* lengths = (const int*)d_in[1];
    const int* blank_ptr = (const int*)d_in[2];

    const int batch = in_sizes[1];
    const int seq_len = (out_size - batch) / batch;      // tokens is (batch, seq_len)
    const int vocab = in_sizes[0] / (seq_len * batch);

    int* tokens = (int*)d_out;                                  // (batch, seq_len)
    int* out_lengths = (int*)d_out + (size_t)batch * seq_len;   // (batch,)
    int* ml = (int*)d_ws;                                       // (batch, seq_len)

    // Kernel 1: 4 rows per wave, 4 waves per 256-thread block.
    constexpr int R = 4;
    const int nrows = seq_len * batch;
    const int nwaves = (nrows + R - 1) / R;
    const int waves_per_block = 4;
    const int blocks1 = (nwaves + waves_per_block - 1) / waves_per_block;
    ctc_argmax_kernel<R><<<blocks1, waves_per_block * 64, 0, stream>>>(
        x, ml, tokens, seq_len, batch, vocab);

    // Kernel 2: one block per batch element.
    ctc_compact_kernel<<<batch, 256, 0, stream>>>(
        ml, lengths, blank_ptr, tokens, out_lengths, seq_len, batch);
}